// Round 19
// baseline (188.131 us; speedup 1.0000x reference)
//
#include <hip/hip_runtime.h>
#include <hip/hip_bf16.h>

#define NH 12
#define SEQ 4096
#define E 768
#define DK 64

typedef float f32x4 __attribute__((ext_vector_type(4)));
typedef float f32x16 __attribute__((ext_vector_type(16)));
typedef __bf16 bf16x8 __attribute__((ext_vector_type(8)));
typedef __bf16 bf16x4 __attribute__((ext_vector_type(4)));
typedef unsigned u32x2 __attribute__((ext_vector_type(2)));
typedef unsigned u32x4 __attribute__((ext_vector_type(4)));

#define MFMA16(a, b, c) __builtin_amdgcn_mfma_f32_16x16x32_bf16((a), (b), (c), 0, 0, 0)
#define MFMA32(a, b, c) __builtin_amdgcn_mfma_f32_32x32x16_bf16((a), (b), (c), 0, 0, 0)

// log2(e) / sqrt(dk); folded into K weights at wsplit time.
#define SCL 0.18033688011112042f
// defer-max threshold in log2 units: P bounded by 2^10.8
#define DEFER 10.8f

#define PART_SZ 4352  // 2*16*64 bf16 (4096B) + m[32],l[32] f32 (256B)

__device__ __forceinline__ void gload16(const void* g, void* l) {
    __builtin_amdgcn_global_load_lds(
        (const __attribute__((address_space(1))) void*)g,
        (__attribute__((address_space(3))) void*)l, 16, 0, 0);
}

__device__ __forceinline__ void block_sync() {
    __builtin_amdgcn_sched_barrier(0);
    __builtin_amdgcn_s_barrier();
    __builtin_amdgcn_sched_barrier(0);
}

__device__ __forceinline__ unsigned cvtpk(float lo, float hi) {
    unsigned r;
    asm("v_cvt_pk_bf16_f32 %0, %1, %2" : "=v"(r) : "v"(lo), "v"(hi));
    return r;
}
__device__ __forceinline__ u32x2 plswap(unsigned a, unsigned b) {
    return __builtin_amdgcn_permlane32_swap(a, b, false, false);
}
__device__ __forceinline__ float xhalf_max(float v) {
    u32x2 r = plswap(__float_as_uint(v), __float_as_uint(v));
    return fmaxf(__uint_as_float(r.x), __uint_as_float(r.y));
}
__device__ __forceinline__ float xhalf_add(float v) {
    u32x2 r = plswap(__float_as_uint(v), __float_as_uint(v));
    return __uint_as_float(r.x) + __uint_as_float(r.y);
}

// ---------------------------------------------------------------------------
// Kernel 1: merged prep. Blocks 0..143: weight split/transpose via LDS
// 64x64 tile (coalesced both sides). Blocks 144..3215: x hi/lo split.
// ---------------------------------------------------------------------------
__global__ __launch_bounds__(256) void prep_kernel(
    const float* __restrict__ x,
    const float* __restrict__ qp, const float* __restrict__ kp,
    const float* __restrict__ vp,
    __bf16* __restrict__ xh, __bf16* __restrict__ xl,
    __bf16* __restrict__ wtq_h, __bf16* __restrict__ wtq_l,
    __bf16* __restrict__ wtk_h, __bf16* __restrict__ wtk_l,
    __bf16* __restrict__ wtv_h) {
    __shared__ float tl[64][65];

    if (blockIdx.x >= 144) {
        int i = (blockIdx.x - 144) * 256 + threadIdx.x;
        float4 v = ((const float4*)x)[i];
        bf16x4 h, l;
        float vv[4] = {v.x, v.y, v.z, v.w};
#pragma unroll
        for (int j = 0; j < 4; ++j) {
            __bf16 hh = (__bf16)vv[j];
            h[j] = hh;
            l[j] = (__bf16)(vv[j] - (float)hh);
        }
        ((bf16x4*)xh)[i] = h;
        ((bf16x4*)xl)[i] = l;
        return;
    }

    const int h = blockIdx.x / 12;
    const int kt = blockIdx.x % 12;
    const int c = threadIdx.x & 63;
    const int r4 = threadIdx.x >> 6;

#pragma unroll
    for (int mat = 0; mat < 3; ++mat) {
        const float* src = ((mat == 0) ? qp : (mat == 1) ? kp : vp)
                         + (size_t)h * E * DK + (size_t)kt * 64 * DK;
        __syncthreads();
#pragma unroll
        for (int i = 0; i < 16; ++i) {
            int row = i * 4 + r4;
            tl[row][c] = src[row * DK + c];
        }
        __syncthreads();
#pragma unroll
        for (int i = 0; i < 16; ++i) {
            int n = i * 4 + r4;
            float v = tl[c][n];
            size_t o = (size_t)h * DK * E + (size_t)n * E + kt * 64 + c;
            if (mat == 0) {
                __bf16 hh = (__bf16)v;
                wtq_h[o] = hh;
                wtq_l[o] = (__bf16)(v - (float)hh);
            } else if (mat == 1) {
                float kk = v * SCL;
                __bf16 hh = (__bf16)kk;
                wtk_h[o] = hh;
                wtk_l[o] = (__bf16)(kk - (float)hh);
            } else {
                wtv_h[o] = (__bf16)v;
            }
        }
    }
}

// ---------------------------------------------------------------------------
// Kernel 2: fused Q+K+V projection, F-SPLIT. Block = 256 thr (4 waves),
// 64 rows; wave w owns output f-tile w (cols 16w..16w+15) for ALL 64 rows
// (rt=4). Per block-kstep ds_reads drop 80 (r17) / 40 (r18) -> 20: each
// wave reads only its own 5 B-frags, zero cross-wave redundancy, same MFMA.
// 3072 waves = 3/SIMD; LDS 40KB -> 4 blocks/CU. Q row-major; K,V FRAG-LINEAR.
// ---------------------------------------------------------------------------
__global__ __launch_bounds__(256, 2) void proj_kernel(
    const __bf16* __restrict__ xh, const __bf16* __restrict__ xl,
    const __bf16* __restrict__ wq_h_g, const __bf16* __restrict__ wq_l_g,
    const __bf16* __restrict__ wk_h_g, const __bf16* __restrict__ wk_l_g,
    const __bf16* __restrict__ wv_g,
    __bf16* __restrict__ qh_o, __bf16* __restrict__ ql_o,
    __bf16* __restrict__ kh_o, __bf16* __restrict__ kl_o,
    __bf16* __restrict__ vt_o) {
    __shared__ char wlds[2][20480];  // [buf][ Wqh | Wql | Wkh | Wkl | Wv ]

    const int wg = (blockIdx.x & 7) * 96 + (blockIdx.x >> 3);  // 768 = 8 x 96
    const int head = wg >> 6;
    const int rb = wg & 63;
    const int wave = threadIdx.x >> 6;  // 0..3 = owned f-tile
    const int lane = threadIdx.x & 63;
    const int lrow = lane & 15;
    const int lk8 = (lane >> 4) * 8;
    const int g4 = (lane >> 4) * 4;
    const int rowbase = rb * 64;  // block's 64 rows (wave spans all via rt)

    const char* bases[5] = {
        (const char*)(wq_h_g + head * DK * E), (const char*)(wq_l_g + head * DK * E),
        (const char*)(wk_h_g + head * DK * E), (const char*)(wk_l_g + head * DK * E),
        (const char*)(wv_g + head * DK * E)};
    const int srow = lane >> 2;
    const int scol = (lane & 3) * 16;

    auto STAGE = [&](int buf, int ks) {
#pragma unroll
        for (int r = 0; r < 5; ++r) {
            int q = wave * 5 + r;  // 0..19
            const char* src = bases[q >> 2] + (size_t)((q & 3) * 16 + srow) * (E * 2) + ks * 64 + scol;
            gload16(src, wlds[buf] + q * 1024 + lane * 16);
        }
    };

    f32x4 accq[4], acck[4], accv[4];
#pragma unroll
    for (int rt = 0; rt < 4; ++rt) {
        accq[rt] = (f32x4){0.f, 0.f, 0.f, 0.f};
        acck[rt] = (f32x4){0.f, 0.f, 0.f, 0.f};
        accv[rt] = (f32x4){0.f, 0.f, 0.f, 0.f};
    }

    bf16x8 ah[4], al[4], ahn[4], aln[4];
    auto LOADA = [&](int ks, bf16x8* h, bf16x8* l) {
#pragma unroll
        for (int rt = 0; rt < 4; ++rt) {
            size_t xo = (size_t)(rowbase + rt * 16 + lrow) * E + ks * 32 + lk8;
            h[rt] = *(const bf16x8*)(xh + xo);
            l[rt] = *(const bf16x8*)(xl + xo);
        }
    };

    LOADA(0, ah, al);
    STAGE(0, 0);
    int buf = 0;
    for (int ks = 0; ks < 24; ++ks) {
        if (ks < 23) {
            LOADA(ks + 1, ahn, aln);
            STAGE(buf ^ 1, ks + 1);
            asm volatile("s_waitcnt vmcnt(13)" ::: "memory");  // 8 LOADA + 5 STAGE
        } else {
            asm volatile("s_waitcnt vmcnt(0)" ::: "memory");
        }
        block_sync();
        {
            int bo = (wave * 16 + lrow) * 64 + lk8 * 2;  // own f-tile only
            bf16x8 bqh = *(const bf16x8*)(wlds[buf] + bo);
            bf16x8 bql = *(const bf16x8*)(wlds[buf] + 4096 + bo);
            bf16x8 bkh = *(const bf16x8*)(wlds[buf] + 8192 + bo);
            bf16x8 bkl = *(const bf16x8*)(wlds[buf] + 12288 + bo);
            bf16x8 bv  = *(const bf16x8*)(wlds[buf] + 16384 + bo);
#pragma unroll
            for (int rt = 0; rt < 4; ++rt) {
                accq[rt] = MFMA16(ah[rt], bqh, accq[rt]);
                accq[rt] = MFMA16(ah[rt], bql, accq[rt]);
                accq[rt] = MFMA16(al[rt], bqh, accq[rt]);
                acck[rt] = MFMA16(ah[rt], bkh, acck[rt]);
                acck[rt] = MFMA16(ah[rt], bkl, acck[rt]);
                acck[rt] = MFMA16(al[rt], bkh, acck[rt]);
                accv[rt] = MFMA16(bv, ah[rt], accv[rt]);  // swapped: D[d][s]
            }
        }
        block_sync();
        if (ks < 23) {
#pragma unroll
            for (int rt = 0; rt < 4; ++rt) {
                ah[rt] = ahn[rt];
                al[rt] = aln[rt];
            }
        }
        buf ^= 1;
    }

    char* khb = (char*)kh_o + (size_t)head * SEQ * DK * 2;
    char* klb = (char*)kl_o + (size_t)head * SEQ * DK * 2;
    char* vb = (char*)vt_o + (size_t)head * DK * SEQ * 2;
#pragma unroll
    for (int rt = 0; rt < 4; ++rt)
#pragma unroll
        for (int r = 0; r < 4; ++r) {
            int srow_o = rowbase + rt * 16 + g4 + r;
            int d = wave * 16 + lrow;
            // Q: row-major
            size_t o = (size_t)head * SEQ * DK + (size_t)srow_o * DK + d;
            float qv = accq[rt][r];
            __bf16 qhh = (__bf16)qv;
            qh_o[o] = qhh;
            ql_o[o] = (__bf16)(qv - (float)qhh);
            // K: fragment-linear
            size_t ko = (size_t)(srow_o >> 6) * 8192 + ((srow_o >> 5) & 1) * 4096
                      + (size_t)wave * 1024
                      + ((srow_o & 31) + 32 * ((lrow >> 3) & 1)) * 16 + (lrow & 7) * 2;
            float kv = acck[rt][r];
            __bf16 khh = (__bf16)kv;
            *(__bf16*)(khb + ko) = khh;
            *(__bf16*)(klb + ko) = (__bf16)(kv - (float)khh);
            // V: fragment-linear (d, key) from swapped accumulator
            int vd = wave * 16 + g4 + r;
            int vs = rowbase + rt * 16 + lrow;
            size_t vo = (size_t)(vs >> 6) * 8192 + ((vd >> 5) & 1) * 4096
                      + ((vs >> 4) & 3) * 1024
                      + ((vd & 31) + 32 * ((vs >> 3) & 1)) * 16 + (vs & 7) * 2;
            *(__bf16*)(vb + vo) = (__bf16)accv[rt][r];
        }
}

// ---------------------------------------------------------------------------
// Kernel 3a: attention partials — r15 proven config (85.3us): fine-grained
// equal-work split-KV, 6912 independent waves, no LDS, no barriers.
// ---------------------------------------------------------------------------
__global__ __launch_bounds__(256, 2) void attn_part_kernel(
    const __bf16* __restrict__ qh, const __bf16* __restrict__ ql,
    const __bf16* __restrict__ kh, const __bf16* __restrict__ kl,
    const __bf16* __restrict__ vt,
    char* __restrict__ part) {
    const int blk = (blockIdx.x & 7) * 216 + (blockIdx.x >> 3);  // 1728 = 8x216
    const int wave = threadIdx.x >> 6;
    const int task = blk * 4 + wave;
    const int lane = threadIdx.x & 63;
    const int lq = lane & 31;
    const int lh = lane >> 5;

    const int head = task / 576;
    const int t = task - head * 576;
    int g = 0;
#pragma unroll 8
    for (int gg = 1; gg <= 7; ++gg)
        if (t >= 16 * gg * (gg + 1) / 2) g = gg;
    const int nsp = g + 1;
    const int u = t - 16 * g * (g + 1) / 2;
    const int w = 16 * g + u / nsp;
    const int split = u - (u / nsp) * nsp;
    const int ktot = (w >> 1) + 1;
    const int lo = (split * ktot) / nsp;
    const int hi = ((split + 1) * ktot) / nsp;
    const int rowbase = w * 32;

    const size_t hoff = (size_t)head * SEQ * DK;

    bf16x8 qBh[4], qBl[4];
    {
        const __bf16* qph = qh + hoff + (size_t)(rowbase + lq) * DK + lh * 8;
        const __bf16* qpl = ql + hoff + (size_t)(rowbase + lq) * DK + lh * 8;
#pragma unroll
        for (int ds = 0; ds < 4; ++ds) {
            qBh[ds] = *(const bf16x8*)(qph + ds * 16);
            qBl[ds] = *(const bf16x8*)(qpl + ds * 16);
        }
    }

    const char* kh_p = (const char*)(kh + hoff) + (size_t)lo * 8192 + lane * 16;
    const char* kl_p = (const char*)(kl + hoff) + (size_t)lo * 8192 + lane * 16;
    const char* vt_p = (const char*)(vt + (size_t)head * DK * SEQ) + (size_t)lo * 8192 + lane * 16;

    f32x16 O0 = (f32x16)0.0f, O1 = (f32x16)0.0f;
    float m = -3.0e38f, lsum = 0.f;

    for (int tt = lo; tt < hi; ++tt) {
        const int kb = tt * 64;

        f32x16 s0 = (f32x16)0.0f, s1 = (f32x16)0.0f;
#pragma unroll
        for (int ds = 0; ds < 4; ++ds) {
            bf16x8 ah0 = *(const bf16x8*)(kh_p + ds * 1024);
            bf16x8 al0 = *(const bf16x8*)(kl_p + ds * 1024);
            bf16x8 ah1 = *(const bf16x8*)(kh_p + 4096 + ds * 1024);
            bf16x8 al1 = *(const bf16x8*)(kl_p + 4096 + ds * 1024);
            s0 = MFMA32(ah0, qBh[ds], s0);
            s1 = MFMA32(ah1, qBh[ds], s1);
            s0 = MFMA32(al0, qBh[ds], s0);
            s1 = MFMA32(al1, qBh[ds], s1);
            s0 = MFMA32(ah0, qBl[ds], s0);
            s1 = MFMA32(ah1, qBl[ds], s1);
        }

        bf16x8 v00 = *(const bf16x8*)(vt_p + 0);
        bf16x8 v01 = *(const bf16x8*)(vt_p + 1024);
        bf16x8 v10 = *(const bf16x8*)(vt_p + 2048);
        bf16x8 v11 = *(const bf16x8*)(vt_p + 3072);
        bf16x8 w00 = *(const bf16x8*)(vt_p + 4096);
        bf16x8 w01 = *(const bf16x8*)(vt_p + 5120);
        bf16x8 w10 = *(const bf16x8*)(vt_p + 6144);
        bf16x8 w11 = *(const bf16x8*)(vt_p + 7168);

        if (kb + 63 > rowbase) {
            int qa = rowbase + lq;
#pragma unroll
            for (int r = 0; r < 16; ++r) {
                int kp = kb + ((r & 3) + 8 * (r >> 2) + 4 * lh);
                if (kp > qa) s0[r] = -1.0e30f;
                if (kp + 32 > qa) s1[r] = -1.0e30f;
            }
        }

        float x0 = fmaxf(s0[0], s0[1]), x1 = fmaxf(s0[2], s0[3]);
        float x2 = fmaxf(s0[4], s0[5]), x3 = fmaxf(s0[6], s0[7]);
#pragma unroll
        for (int r = 8; r < 16; r += 4) {
            x0 = fmaxf(x0, fmaxf(s0[r], s0[r + 1]));
            x1 = fmaxf(x1, fmaxf(s0[r + 2], s0[r + 3]));
        }
#pragma unroll
        for (int r = 0; r < 16; r += 4) {
            x2 = fmaxf(x2, fmaxf(s1[r], s1[r + 1]));
            x3 = fmaxf(x3, fmaxf(s1[r + 2], s1[r + 3]));
        }
        float mx = xhalf_max(fmaxf(fmaxf(x0, x1), fmaxf(x2, x3)));

        if (!__all(mx - m <= DEFER)) {
            float mn = fmaxf(m, mx);
            float al = exp2f(m - mn);
            m = mn;
            lsum *= al;
#pragma unroll
            for (int r = 0; r < 16; ++r) {
                float a = __shfl(al, (r & 3) + 8 * (r >> 2) + 4 * lh);
                O0[r] *= a;
                O1[r] *= a;
            }
        }

        s0 = s0 - m;
        s1 = s1 - m;
#pragma unroll
        for (int r = 0; r < 16; ++r) {
            s0[r] = exp2f(s0[r]);
            s1[r] = exp2f(s1[r]);
        }
        {
            f32x16 sv = s0 + s1;
            float p0 = 0.f, p1 = 0.f;
#pragma unroll
            for (int r = 0; r < 16; r += 4) {
                p0 += sv[r] + sv[r + 1];
                p1 += sv[r + 2] + sv[r + 3];
            }
            lsum += p0 + p1;
        }

        unsigned W0 = cvtpk(s0[0], s0[1]), W1 = cvtpk(s0[2], s0[3]);
        unsigned W2 = cvtpk(s0[4], s0[5]), W3 = cvtpk(s0[6], s0[7]);
        unsigned W4 = cvtpk(s0[8], s0[9]), W5 = cvtpk(s0[10], s0[11]);
        unsigned W6 = cvtpk(s0[12], s0[13]), W7 = cvtpk(s0[14], s0[15]);
        u32x2 rA = plswap(W0, W2), rB = plswap(W1, W3);
        u32x2 rC = plswap(W4, W6), rD = plswap(W5, W7);
        bf16x8 p00 = __builtin_bit_cast(bf16x8, (u32x4){rA.x, rB.x, rA.y, rB.y});
        bf16x8 p01 = __builtin_bit_cast(bf16x8, (u32x4){rC.x, rD.x, rC.y, rD.y});
        W0 = cvtpk(s1[0], s1[1]); W1 = cvtpk(s1[2], s1[3]);
        W2 = cvtpk(s1[4], s1[5]); W3 = cvtpk(s1[6], s1[7]);
        W4 = cvtpk(s1[8], s1[9]); W5 = cvtpk(s1[10], s1[11]);
        W6 = cvtpk(s1[12], s1[13]); W7 = cvtpk(s1[14], s1[15]);
        rA = plswap(W0, W2); rB = plswap(W1, W3);
        rC = plswap(W4, W6); rD = plswap(W5, W7);
        bf16x8 p10 = __builtin_bit_cast(bf16x8, (u32x4){rA.x, rB.x, rA.y, rB.y});
        bf16x8 p11 = __builtin_bit_cast(bf16x8, (u32x4){rC.x, rD.x, rC.y, rD.y});

        O0 = MFMA32(p00, v00, O0);
        O0 = MFMA32(p01, v01, O0);
        O0 = MFMA32(p10, v10, O0);
        O0 = MFMA32(p11, v11, O0);
        O1 = MFMA32(p00, w00, O1);
        O1 = MFMA32(p01, w01, O1);
        O1 = MFMA32(p10, w10, O1);
        O1 = MFMA32(p11, w11, O1);

        kh_p += 8192;
        kl_p += 8192;
        vt_p += 8192;
    }

    char* pb = part + (size_t)task * PART_SZ;
    unsigned* ph = (unsigned*)pb;
#pragma unroll
    for (int r = 0; r < 16; r += 2) {
        ph[(r >> 1) * 64 + lane] = cvtpk(O0[r], O0[r + 1]);
        ph[512 + (r >> 1) * 64 + lane] = cvtpk(O1[r], O1[r + 1]);
    }
    float lf = xhalf_add(lsum);
    float* pm = (float*)(pb + 4096);
    if (lane < 32) {
        pm[lq] = m;
        pm[32 + lq] = lf;
    }
}

// ---------------------------------------------------------------------------
// Kernel 3b: combine partials — exact flash merge per (head, window).
// Two-pass, array-free (rule #20). r15 indexing (G=16 tiering).
// ---------------------------------------------------------------------------
__global__ __launch_bounds__(256) void attn_comb_kernel(
    const char* __restrict__ part, float* __restrict__ out) {
    const int W = blockIdx.x;  // 0..1535
    const int head = W >> 7, w = W & 127;
    const int g = w >> 4;
    const int nsp = g + 1;
    const int tb = head * 576 + 16 * g * (g + 1) / 2 + (w - 16 * g) * nsp;

    const int tid = threadIdx.x;
    const int row = tid >> 3;
    const int d0 = (tid & 7) * 8;
    const int lane0 = (d0 & 31) + 32 * ((row >> 2) & 1);
    const int r = (row & 3) + 4 * (row >> 3);
    const int word = (r >> 1) * 64;
    const int hi16 = r & 1;
    const char* p0 = part + (size_t)tb * PART_SZ;

    float mstar = -3.0e38f;
    for (int s = 0; s < nsp; ++s) {
        const float* pm = (const float*)(p0 + s * PART_SZ + 4096);
        mstar = fmaxf(mstar, pm[row]);
    }

    float acc[8] = {0.f, 0.f, 0.f, 0.f, 0.f, 0.f, 0.f, 0.f};
    float lt = 0.f;
    for (int s = 0; s < nsp; ++s) {
        const char* ps = p0 + s * PART_SZ;
        const float* pm = (const float*)(ps + 4096);
        float wgt = exp2f(pm[row] - mstar);
        lt += wgt * pm[32 + row];
        const unsigned* pw = (const unsigned*)(ps + (d0 >> 5) * 2048);
        u32x4 a = *(const u32x4*)(pw + word + lane0);
        u32x4 b = *(const u32x4*)(pw + word + lane0 + 4);
#pragma unroll
        for (int j = 0; j < 8; ++j) {
            unsigned u = (j < 4) ? a[j] : b[j - 4];
            unsigned bits = hi16 ? (u & 0xffff0000u) : (u << 16);
            acc[j] += wgt * __uint_as_float(bits);
        }
    }
    float inv = 1.0f / lt;
    size_t o = (size_t)head * SEQ * DK + (size_t)(w * 32 + row) * DK + d0;
#pragma unroll
    for (int j = 0; j < 8; ++j) out[o + j] = acc[j] * inv;
}

// ---------------------------------------------------------------------------
extern "C" void kernel_launch(void* const* d_in, const int* in_sizes, int n_in,
                              void* d_out, int out_size, void* d_ws, size_t ws_size,
                              hipStream_t stream) {
    const float* x = (const float*)d_in[0];
    const float* qp = (const float*)d_in[1];
    const float* kp = (const float*)d_in[2];
    const float* vp = (const float*)d_in[3];
    float* out = (float*)d_out;

    const size_t WT_SZ = (size_t)NH * DK * E * 2;     // 1,179,648 B
    const size_t QKV_SZ = (size_t)NH * SEQ * DK * 2;  // 6,291,456 B
    const size_t X_SZ = (size_t)SEQ * E * 2;          // 6,291,456 B
    char* ws = (char*)d_ws;
    __bf16* wtq_h = (__bf16*)(ws + 0 * WT_SZ);
    __bf16* wtq_l = (__bf16*)(ws + 1 * WT_SZ);
    __bf16* wtk_h = (__bf16*)(ws + 2 * WT_SZ);
    __bf16* wtk_l = (__bf16*)(ws + 3 * WT_SZ);
    __bf16* wtv_h = (__bf16*)(ws + 4 * WT_SZ);
    char* px = ws + 5 * WT_SZ;
    __bf16* xh = (__bf16*)(px + 0 * X_SZ);
    __bf16* xl = (__bf16*)(px + 1 * X_SZ);
    char* p2 = px + 2 * X_SZ;  // 18,481,152
    __bf16* qh = (__bf16*)(p2 + 0 * QKV_SZ);
    __bf16* ql = (__bf16*)(p2 + 1 * QKV_SZ);
    __bf16* kh = (__bf16*)(p2 + 2 * QKV_SZ);
    __bf16* kl = (__bf16*)(p2 + 3 * QKV_SZ);
    __bf16* vt = (__bf16*)(p2 + 4 * QKV_SZ);
    char* part = p2 + 5 * QKV_SZ;  // 6912 x 4352 = 30,081,024 B (ws-verified r15)

    hipLaunchKernelGGL(prep_kernel, dim3(144 + SEQ * E / 4 / 256), dim3(256), 0, stream,
                       x, qp, kp, vp, xh, xl, wtq_h, wtq_l, wtk_h, wtk_l, wtv_h);
    hipLaunchKernelGGL(proj_kernel, dim3(768), dim3(256), 0, stream,
                       xh, xl, wtq_h, wtq_l, wtk_h, wtk_l, wtv_h, qh, ql, kh, kl, vt);
    hipLaunchKernelGGL(attn_part_kernel, dim3(1728), dim3(256), 0, stream,
                       qh, ql, kh, kl, vt, part);
    hipLaunchKernelGGL(attn_comb_kernel, dim3(1536), dim3(256), 0, stream,
                       part, out);
}

// Round 20
// 151.273 us; speedup vs baseline: 1.2436x; 1.2436x over previous
//
#include <hip/hip_runtime.h>
#include <hip/hip_bf16.h>

#define NH 12
#define SEQ 4096
#define E 768
#define DK 64

typedef float f32x4 __attribute__((ext_vector_type(4)));
typedef float f32x16 __attribute__((ext_vector_type(16)));
typedef __bf16 bf16x8 __attribute__((ext_vector_type(8)));
typedef __bf16 bf16x4 __attribute__((ext_vector_type(4)));
typedef unsigned u32x2 __attribute__((ext_vector_type(2)));
typedef unsigned u32x4 __attribute__((ext_vector_type(4)));

#define MFMA16(a, b, c) __builtin_amdgcn_mfma_f32_16x16x32_bf16((a), (b), (c), 0, 0, 0)
#define MFMA32(a, b, c) __builtin_amdgcn_mfma_f32_32x32x16_bf16((a), (b), (c), 0, 0, 0)

// log2(e) / sqrt(dk); folded into K weights at wsplit time.
#define SCL 0.18033688011112042f
// defer-max threshold in log2 units: P bounded by 2^10.8
#define DEFER 10.8f

#define PART_SZ 4352  // 2*16*64 bf16 (4096B) + m[32],l[32] f32 (256B)

__device__ __forceinline__ void gload16(const void* g, void* l) {
    __builtin_amdgcn_global_load_lds(
        (const __attribute__((address_space(1))) void*)g,
        (__attribute__((address_space(3))) void*)l, 16, 0, 0);
}

__device__ __forceinline__ void block_sync() {
    __builtin_amdgcn_sched_barrier(0);
    __builtin_amdgcn_s_barrier();
    __builtin_amdgcn_sched_barrier(0);
}

__device__ __forceinline__ unsigned cvtpk(float lo, float hi) {
    unsigned r;
    asm("v_cvt_pk_bf16_f32 %0, %1, %2" : "=v"(r) : "v"(lo), "v"(hi));
    return r;
}
__device__ __forceinline__ u32x2 plswap(unsigned a, unsigned b) {
    return __builtin_amdgcn_permlane32_swap(a, b, false, false);
}
__device__ __forceinline__ float xhalf_max(float v) {
    u32x2 r = plswap(__float_as_uint(v), __float_as_uint(v));
    return fmaxf(__uint_as_float(r.x), __uint_as_float(r.y));
}
__device__ __forceinline__ float xhalf_add(float v) {
    u32x2 r = plswap(__float_as_uint(v), __float_as_uint(v));
    return __uint_as_float(r.x) + __uint_as_float(r.y);
}

// ---------------------------------------------------------------------------
// Kernel 1: merged prep. Blocks 0..143: weight split/transpose via LDS
// 64x64 tile (coalesced both sides). Blocks 144..3215: x hi/lo split.
// ---------------------------------------------------------------------------
__global__ __launch_bounds__(256) void prep_kernel(
    const float* __restrict__ x,
    const float* __restrict__ qp, const float* __restrict__ kp,
    const float* __restrict__ vp,
    __bf16* __restrict__ xh, __bf16* __restrict__ xl,
    __bf16* __restrict__ wtq_h, __bf16* __restrict__ wtq_l,
    __bf16* __restrict__ wtk_h, __bf16* __restrict__ wtk_l,
    __bf16* __restrict__ wtv_h) {
    __shared__ float tl[64][65];

    if (blockIdx.x >= 144) {
        int i = (blockIdx.x - 144) * 256 + threadIdx.x;
        float4 v = ((const float4*)x)[i];
        bf16x4 h, l;
        float vv[4] = {v.x, v.y, v.z, v.w};
#pragma unroll
        for (int j = 0; j < 4; ++j) {
            __bf16 hh = (__bf16)vv[j];
            h[j] = hh;
            l[j] = (__bf16)(vv[j] - (float)hh);
        }
        ((bf16x4*)xh)[i] = h;
        ((bf16x4*)xl)[i] = l;
        return;
    }

    const int h = blockIdx.x / 12;
    const int kt = blockIdx.x % 12;
    const int c = threadIdx.x & 63;
    const int r4 = threadIdx.x >> 6;

#pragma unroll
    for (int mat = 0; mat < 3; ++mat) {
        const float* src = ((mat == 0) ? qp : (mat == 1) ? kp : vp)
                         + (size_t)h * E * DK + (size_t)kt * 64 * DK;
        __syncthreads();
#pragma unroll
        for (int i = 0; i < 16; ++i) {
            int row = i * 4 + r4;
            tl[row][c] = src[row * DK + c];
        }
        __syncthreads();
#pragma unroll
        for (int i = 0; i < 16; ++i) {
            int n = i * 4 + r4;
            float v = tl[c][n];
            size_t o = (size_t)h * DK * E + (size_t)n * E + kt * 64 + c;
            if (mat == 0) {
                __bf16 hh = (__bf16)v;
                wtq_h[o] = hh;
                wtq_l[o] = (__bf16)(v - (float)hh);
            } else if (mat == 1) {
                float kk = v * SCL;
                __bf16 hh = (__bf16)kk;
                wtk_h[o] = hh;
                wtk_l[o] = (__bf16)(kk - (float)hh);
            } else {
                wtv_h[o] = (__bf16)v;
            }
        }
    }
}

// ---------------------------------------------------------------------------
// Kernel 2: fused Q+K+V projection (r18-proven). Block = 128 thr (2 waves x
// 32 rows), 64 rows/block, grid 768. x read exactly once per block (r19's
// f-split duplicated x 4x -> 79MB fetch, reverted). Q row-major; K,V
// FRAGMENT-LINEAR.
// ---------------------------------------------------------------------------
__global__ __launch_bounds__(128, 2) void proj_kernel(
    const __bf16* __restrict__ xh, const __bf16* __restrict__ xl,
    const __bf16* __restrict__ wq_h_g, const __bf16* __restrict__ wq_l_g,
    const __bf16* __restrict__ wk_h_g, const __bf16* __restrict__ wk_l_g,
    const __bf16* __restrict__ wv_g,
    __bf16* __restrict__ qh_o, __bf16* __restrict__ ql_o,
    __bf16* __restrict__ kh_o, __bf16* __restrict__ kl_o,
    __bf16* __restrict__ vt_o) {
    __shared__ char wlds[2][20480];  // [buf][ Wqh | Wql | Wkh | Wkl | Wv ]

    const int wg = (blockIdx.x & 7) * 96 + (blockIdx.x >> 3);  // 768 = 8 x 96
    const int head = wg >> 6;
    const int rb = wg & 63;
    const int wave = threadIdx.x >> 6;  // 0..1
    const int lane = threadIdx.x & 63;
    const int lrow = lane & 15;
    const int lk8 = (lane >> 4) * 8;
    const int g4 = (lane >> 4) * 4;
    const int rowbase = rb * 64 + wave * 32;  // wave's 32 rows

    const char* bases[5] = {
        (const char*)(wq_h_g + head * DK * E), (const char*)(wq_l_g + head * DK * E),
        (const char*)(wk_h_g + head * DK * E), (const char*)(wk_l_g + head * DK * E),
        (const char*)(wv_g + head * DK * E)};
    const int srow = lane >> 2;
    const int scol = (lane & 3) * 16;

    auto STAGE = [&](int buf, int ks) {
#pragma unroll
        for (int r = 0; r < 10; ++r) {
            int q = wave * 10 + r;  // 0..19
            const char* src = bases[q >> 2] + (size_t)((q & 3) * 16 + srow) * (E * 2) + ks * 64 + scol;
            gload16(src, wlds[buf] + q * 1024 + lane * 16);
        }
    };

    f32x4 accq[2][4], acck[2][4], accv[2][4];
#pragma unroll
    for (int rt = 0; rt < 2; ++rt)
#pragma unroll
        for (int f = 0; f < 4; ++f) {
            accq[rt][f] = (f32x4){0.f, 0.f, 0.f, 0.f};
            acck[rt][f] = (f32x4){0.f, 0.f, 0.f, 0.f};
            accv[rt][f] = (f32x4){0.f, 0.f, 0.f, 0.f};
        }

    bf16x8 ah[2], al[2], ahn[2], aln[2];
    auto LOADA = [&](int ks, bf16x8* h, bf16x8* l) {
#pragma unroll
        for (int rt = 0; rt < 2; ++rt) {
            size_t xo = (size_t)(rowbase + rt * 16 + lrow) * E + ks * 32 + lk8;
            h[rt] = *(const bf16x8*)(xh + xo);
            l[rt] = *(const bf16x8*)(xl + xo);
        }
    };

    LOADA(0, ah, al);
    STAGE(0, 0);
    int buf = 0;
    for (int ks = 0; ks < 24; ++ks) {
        if (ks < 23) {
            LOADA(ks + 1, ahn, aln);
            STAGE(buf ^ 1, ks + 1);
            asm volatile("s_waitcnt vmcnt(14)" ::: "memory");  // 10 stage + 4 x
        } else {
            asm volatile("s_waitcnt vmcnt(0)" ::: "memory");
        }
        block_sync();
#pragma unroll
        for (int f = 0; f < 4; ++f) {
            int bo = (f * 16 + lrow) * 64 + lk8 * 2;
            bf16x8 bqh = *(const bf16x8*)(wlds[buf] + bo);
            bf16x8 bql = *(const bf16x8*)(wlds[buf] + 4096 + bo);
            bf16x8 bkh = *(const bf16x8*)(wlds[buf] + 8192 + bo);
            bf16x8 bkl = *(const bf16x8*)(wlds[buf] + 12288 + bo);
            bf16x8 bv  = *(const bf16x8*)(wlds[buf] + 16384 + bo);
#pragma unroll
            for (int rt = 0; rt < 2; ++rt) {
                accq[rt][f] = MFMA16(ah[rt], bqh, accq[rt][f]);
                accq[rt][f] = MFMA16(ah[rt], bql, accq[rt][f]);
                accq[rt][f] = MFMA16(al[rt], bqh, accq[rt][f]);
                acck[rt][f] = MFMA16(ah[rt], bkh, acck[rt][f]);
                acck[rt][f] = MFMA16(ah[rt], bkl, acck[rt][f]);
                acck[rt][f] = MFMA16(al[rt], bkh, acck[rt][f]);
                accv[rt][f] = MFMA16(bv, ah[rt], accv[rt][f]);  // D[d][s]
            }
        }
        block_sync();
        if (ks < 23) {
#pragma unroll
            for (int rt = 0; rt < 2; ++rt) {
                ah[rt] = ahn[rt];
                al[rt] = aln[rt];
            }
        }
        buf ^= 1;
    }

    char* khb = (char*)kh_o + (size_t)head * SEQ * DK * 2;
    char* klb = (char*)kl_o + (size_t)head * SEQ * DK * 2;
    char* vb = (char*)vt_o + (size_t)head * DK * SEQ * 2;
#pragma unroll
    for (int rt = 0; rt < 2; ++rt)
#pragma unroll
        for (int f = 0; f < 4; ++f)
#pragma unroll
            for (int r = 0; r < 4; ++r) {
                int srow_o = rowbase + rt * 16 + g4 + r;
                int d = f * 16 + lrow;
                size_t o = (size_t)head * SEQ * DK + (size_t)srow_o * DK + d;
                float qv = accq[rt][f][r];
                __bf16 qhh = (__bf16)qv;
                qh_o[o] = qhh;
                ql_o[o] = (__bf16)(qv - (float)qhh);
                size_t ko = (size_t)(srow_o >> 6) * 8192 + ((srow_o >> 5) & 1) * 4096
                          + (size_t)f * 1024
                          + ((srow_o & 31) + 32 * ((lrow >> 3) & 1)) * 16 + (lrow & 7) * 2;
                float kv = acck[rt][f][r];
                __bf16 khh = (__bf16)kv;
                *(__bf16*)(khb + ko) = khh;
                *(__bf16*)(klb + ko) = (__bf16)(kv - (float)khh);
                int vd = f * 16 + g4 + r;
                int vs = rowbase + rt * 16 + lrow;
                size_t vo = (size_t)(vs >> 6) * 8192 + ((vd >> 5) & 1) * 4096
                          + ((vs >> 4) & 3) * 1024
                          + ((vd & 31) + 32 * ((vs >> 3) & 1)) * 16 + (vs & 7) * 2;
                *(__bf16*)(vb + vo) = (__bf16)accv[rt][f][r];
            }
}

// ---------------------------------------------------------------------------
// Kernel 3a: attention partials — r15 structure (no LDS, no barriers,
// 6912 equal-work tasks) + L1 CO-LOCATION remap: within a tier the task
// index is now split*16 + window-offset, so a block's 4 waves are 4
// CONSECUTIVE WINDOWS with the SAME split -> nearly identical KV ranges,
// read in lockstep -> ~3/4 of K/V reads become L1 hits (a 24KB tile fits
// the 32KB L1). Attacks the measured L2-service wall (1.2GB @ ~14TB/s)
// without the LDS/barrier/occupancy cost that nulled r16/r17.
// ---------------------------------------------------------------------------
__global__ __launch_bounds__(256, 2) void attn_part_kernel(
    const __bf16* __restrict__ qh, const __bf16* __restrict__ ql,
    const __bf16* __restrict__ kh, const __bf16* __restrict__ kl,
    const __bf16* __restrict__ vt,
    char* __restrict__ part) {
    const int blk = (blockIdx.x & 7) * 216 + (blockIdx.x >> 3);  // 1728 = 8x216
    const int wave = threadIdx.x >> 6;
    const int task = blk * 4 + wave;
    const int lane = threadIdx.x & 63;
    const int lq = lane & 31;
    const int lh = lane >> 5;

    const int head = task / 576;
    const int t = task - head * 576;
    int g = 0;
#pragma unroll 8
    for (int gg = 1; gg <= 7; ++gg)
        if (t >= 16 * gg * (gg + 1) / 2) g = gg;
    const int nsp = g + 1;
    const int u = t - 16 * g * (g + 1) / 2;
    const int split = u >> 4;            // CO-LOCATION: split-major
    const int w = 16 * g + (u & 15);     // 4 consecutive windows per block
    const int ktot = (w >> 1) + 1;
    const int lo = (split * ktot) / nsp;
    const int hi = ((split + 1) * ktot) / nsp;
    const int rowbase = w * 32;

    const size_t hoff = (size_t)head * SEQ * DK;

    bf16x8 qBh[4], qBl[4];
    {
        const __bf16* qph = qh + hoff + (size_t)(rowbase + lq) * DK + lh * 8;
        const __bf16* qpl = ql + hoff + (size_t)(rowbase + lq) * DK + lh * 8;
#pragma unroll
        for (int ds = 0; ds < 4; ++ds) {
            qBh[ds] = *(const bf16x8*)(qph + ds * 16);
            qBl[ds] = *(const bf16x8*)(qpl + ds * 16);
        }
    }

    const char* kh_p = (const char*)(kh + hoff) + (size_t)lo * 8192 + lane * 16;
    const char* kl_p = (const char*)(kl + hoff) + (size_t)lo * 8192 + lane * 16;
    const char* vt_p = (const char*)(vt + (size_t)head * DK * SEQ) + (size_t)lo * 8192 + lane * 16;

    f32x16 O0 = (f32x16)0.0f, O1 = (f32x16)0.0f;
    float m = -3.0e38f, lsum = 0.f;

    for (int tt = lo; tt < hi; ++tt) {
        const int kb = tt * 64;

        f32x16 s0 = (f32x16)0.0f, s1 = (f32x16)0.0f;
#pragma unroll
        for (int ds = 0; ds < 4; ++ds) {
            bf16x8 ah0 = *(const bf16x8*)(kh_p + ds * 1024);
            bf16x8 al0 = *(const bf16x8*)(kl_p + ds * 1024);
            bf16x8 ah1 = *(const bf16x8*)(kh_p + 4096 + ds * 1024);
            bf16x8 al1 = *(const bf16x8*)(kl_p + 4096 + ds * 1024);
            s0 = MFMA32(ah0, qBh[ds], s0);
            s1 = MFMA32(ah1, qBh[ds], s1);
            s0 = MFMA32(al0, qBh[ds], s0);
            s1 = MFMA32(al1, qBh[ds], s1);
            s0 = MFMA32(ah0, qBl[ds], s0);
            s1 = MFMA32(ah1, qBl[ds], s1);
        }

        bf16x8 v00 = *(const bf16x8*)(vt_p + 0);
        bf16x8 v01 = *(const bf16x8*)(vt_p + 1024);
        bf16x8 v10 = *(const bf16x8*)(vt_p + 2048);
        bf16x8 v11 = *(const bf16x8*)(vt_p + 3072);
        bf16x8 w00 = *(const bf16x8*)(vt_p + 4096);
        bf16x8 w01 = *(const bf16x8*)(vt_p + 5120);
        bf16x8 w10 = *(const bf16x8*)(vt_p + 6144);
        bf16x8 w11 = *(const bf16x8*)(vt_p + 7168);

        if (kb + 63 > rowbase) {
            int qa = rowbase + lq;
#pragma unroll
            for (int r = 0; r < 16; ++r) {
                int kp = kb + ((r & 3) + 8 * (r >> 2) + 4 * lh);
                if (kp > qa) s0[r] = -1.0e30f;
                if (kp + 32 > qa) s1[r] = -1.0e30f;
            }
        }

        float x0 = fmaxf(s0[0], s0[1]), x1 = fmaxf(s0[2], s0[3]);
        float x2 = fmaxf(s0[4], s0[5]), x3 = fmaxf(s0[6], s0[7]);
#pragma unroll
        for (int r = 8; r < 16; r += 4) {
            x0 = fmaxf(x0, fmaxf(s0[r], s0[r + 1]));
            x1 = fmaxf(x1, fmaxf(s0[r + 2], s0[r + 3]));
        }
#pragma unroll
        for (int r = 0; r < 16; r += 4) {
            x2 = fmaxf(x2, fmaxf(s1[r], s1[r + 1]));
            x3 = fmaxf(x3, fmaxf(s1[r + 2], s1[r + 3]));
        }
        float mx = xhalf_max(fmaxf(fmaxf(x0, x1), fmaxf(x2, x3)));

        if (!__all(mx - m <= DEFER)) {
            float mn = fmaxf(m, mx);
            float al = exp2f(m - mn);
            m = mn;
            lsum *= al;
#pragma unroll
            for (int r = 0; r < 16; ++r) {
                float a = __shfl(al, (r & 3) + 8 * (r >> 2) + 4 * lh);
                O0[r] *= a;
                O1[r] *= a;
            }
        }

        s0 = s0 - m;
        s1 = s1 - m;
#pragma unroll
        for (int r = 0; r < 16; ++r) {
            s0[r] = exp2f(s0[r]);
            s1[r] = exp2f(s1[r]);
        }
        {
            f32x16 sv = s0 + s1;
            float p0 = 0.f, p1 = 0.f;
#pragma unroll
            for (int r = 0; r < 16; r += 4) {
                p0 += sv[r] + sv[r + 1];
                p1 += sv[r + 2] + sv[r + 3];
            }
            lsum += p0 + p1;
        }

        unsigned W0 = cvtpk(s0[0], s0[1]), W1 = cvtpk(s0[2], s0[3]);
        unsigned W2 = cvtpk(s0[4], s0[5]), W3 = cvtpk(s0[6], s0[7]);
        unsigned W4 = cvtpk(s0[8], s0[9]), W5 = cvtpk(s0[10], s0[11]);
        unsigned W6 = cvtpk(s0[12], s0[13]), W7 = cvtpk(s0[14], s0[15]);
        u32x2 rA = plswap(W0, W2), rB = plswap(W1, W3);
        u32x2 rC = plswap(W4, W6), rD = plswap(W5, W7);
        bf16x8 p00 = __builtin_bit_cast(bf16x8, (u32x4){rA.x, rB.x, rA.y, rB.y});
        bf16x8 p01 = __builtin_bit_cast(bf16x8, (u32x4){rC.x, rD.x, rC.y, rD.y});
        W0 = cvtpk(s1[0], s1[1]); W1 = cvtpk(s1[2], s1[3]);
        W2 = cvtpk(s1[4], s1[5]); W3 = cvtpk(s1[6], s1[7]);
        W4 = cvtpk(s1[8], s1[9]); W5 = cvtpk(s1[10], s1[11]);
        W6 = cvtpk(s1[12], s1[13]); W7 = cvtpk(s1[14], s1[15]);
        rA = plswap(W0, W2); rB = plswap(W1, W3);
        rC = plswap(W4, W6); rD = plswap(W5, W7);
        bf16x8 p10 = __builtin_bit_cast(bf16x8, (u32x4){rA.x, rB.x, rA.y, rB.y});
        bf16x8 p11 = __builtin_bit_cast(bf16x8, (u32x4){rC.x, rD.x, rC.y, rD.y});

        O0 = MFMA32(p00, v00, O0);
        O0 = MFMA32(p01, v01, O0);
        O0 = MFMA32(p10, v10, O0);
        O0 = MFMA32(p11, v11, O0);
        O1 = MFMA32(p00, w00, O1);
        O1 = MFMA32(p01, w01, O1);
        O1 = MFMA32(p10, w10, O1);
        O1 = MFMA32(p11, w11, O1);

        kh_p += 8192;
        kl_p += 8192;
        vt_p += 8192;
    }

    char* pb = part + (size_t)task * PART_SZ;
    unsigned* ph = (unsigned*)pb;
#pragma unroll
    for (int r = 0; r < 16; r += 2) {
        ph[(r >> 1) * 64 + lane] = cvtpk(O0[r], O0[r + 1]);
        ph[512 + (r >> 1) * 64 + lane] = cvtpk(O1[r], O1[r + 1]);
    }
    float lf = xhalf_add(lsum);
    float* pm = (float*)(pb + 4096);
    if (lane < 32) {
        pm[lq] = m;
        pm[32 + lq] = lf;
    }
}

// ---------------------------------------------------------------------------
// Kernel 3b: combine partials — exact flash merge per (head, window).
// Split-major task layout: window w's partial s lives at
// (head*576 + tierbase + s*16 + (w&15)) * PART_SZ.
// ---------------------------------------------------------------------------
__global__ __launch_bounds__(256) void attn_comb_kernel(
    const char* __restrict__ part, float* __restrict__ out) {
    const int W = blockIdx.x;  // 0..1535
    const int head = W >> 7, w = W & 127;
    const int g = w >> 4;
    const int nsp = g + 1;
    const int tb = head * 576 + 16 * g * (g + 1) / 2 + (w & 15);

    const int tid = threadIdx.x;
    const int row = tid >> 3;
    const int d0 = (tid & 7) * 8;
    const int lane0 = (d0 & 31) + 32 * ((row >> 2) & 1);
    const int r = (row & 3) + 4 * (row >> 3);
    const int word = (r >> 1) * 64;
    const int hi16 = r & 1;
    const char* p0 = part + (size_t)tb * PART_SZ;

    float mstar = -3.0e38f;
    for (int s = 0; s < nsp; ++s) {
        const float* pm = (const float*)(p0 + (size_t)s * 16 * PART_SZ + 4096);
        mstar = fmaxf(mstar, pm[row]);
    }

    float acc[8] = {0.f, 0.f, 0.f, 0.f, 0.f, 0.f, 0.f, 0.f};
    float lt = 0.f;
    for (int s = 0; s < nsp; ++s) {
        const char* ps = p0 + (size_t)s * 16 * PART_SZ;
        const float* pm = (const float*)(ps + 4096);
        float wgt = exp2f(pm[row] - mstar);
        lt += wgt * pm[32 + row];
        const unsigned* pw = (const unsigned*)(ps + (d0 >> 5) * 2048);
        u32x4 a = *(const u32x4*)(pw + word + lane0);
        u32x4 b = *(const u32x4*)(pw + word + lane0 + 4);
#pragma unroll
        for (int j = 0; j < 8; ++j) {
            unsigned u = (j < 4) ? a[j] : b[j - 4];
            unsigned bits = hi16 ? (u & 0xffff0000u) : (u << 16);
            acc[j] += wgt * __uint_as_float(bits);
        }
    }
    float inv = 1.0f / lt;
    size_t o = (size_t)head * SEQ * DK + (size_t)(w * 32 + row) * DK + d0;
#pragma unroll
    for (int j = 0; j < 8; ++j) out[o + j] = acc[j] * inv;
}

// ---------------------------------------------------------------------------
extern "C" void kernel_launch(void* const* d_in, const int* in_sizes, int n_in,
                              void* d_out, int out_size, void* d_ws, size_t ws_size,
                              hipStream_t stream) {
    const float* x = (const float*)d_in[0];
    const float* qp = (const float*)d_in[1];
    const float* kp = (const float*)d_in[2];
    const float* vp = (const float*)d_in[3];
    float* out = (float*)d_out;

    const size_t WT_SZ = (size_t)NH * DK * E * 2;     // 1,179,648 B
    const size_t QKV_SZ = (size_t)NH * SEQ * DK * 2;  // 6,291,456 B
    const size_t X_SZ = (size_t)SEQ * E * 2;          // 6,291,456 B
    char* ws = (char*)d_ws;
    __bf16* wtq_h = (__bf16*)(ws + 0 * WT_SZ);
    __bf16* wtq_l = (__bf16*)(ws + 1 * WT_SZ);
    __bf16* wtk_h = (__bf16*)(ws + 2 * WT_SZ);
    __bf16* wtk_l = (__bf16*)(ws + 3 * WT_SZ);
    __bf16* wtv_h = (__bf16*)(ws + 4 * WT_SZ);
    char* px = ws + 5 * WT_SZ;
    __bf16* xh = (__bf16*)(px + 0 * X_SZ);
    __bf16* xl = (__bf16*)(px + 1 * X_SZ);
    char* p2 = px + 2 * X_SZ;  // 18,481,152
    __bf16* qh = (__bf16*)(p2 + 0 * QKV_SZ);
    __bf16* ql = (__bf16*)(p2 + 1 * QKV_SZ);
    __bf16* kh = (__bf16*)(p2 + 2 * QKV_SZ);
    __bf16* kl = (__bf16*)(p2 + 3 * QKV_SZ);
    __bf16* vt = (__bf16*)(p2 + 4 * QKV_SZ);
    char* part = p2 + 5 * QKV_SZ;  // 6912 x 4352 = 30,081,024 B (ws-verified r15)

    hipLaunchKernelGGL(prep_kernel, dim3(144 + SEQ * E / 4 / 256), dim3(256), 0, stream,
                       x, qp, kp, vp, xh, xl, wtq_h, wtq_l, wtk_h, wtk_l, wtv_h);
    hipLaunchKernelGGL(proj_kernel, dim3(768), dim3(128), 0, stream,
                       xh, xl, wtq_h, wtq_l, wtk_h, wtk_l, wtv_h, qh, ql, kh, kl, vt);
    hipLaunchKernelGGL(attn_part_kernel, dim3(1728), dim3(256), 0, stream,
                       qh, ql, kh, kl, vt, part);
    hipLaunchKernelGGL(attn_comb_kernel, dim3(1536), dim3(256), 0, stream,
                       part, out);
}

// Round 21
// 146.565 us; speedup vs baseline: 1.2836x; 1.0321x over previous
//
#include <hip/hip_runtime.h>
#include <hip/hip_bf16.h>

#define NH 12
#define SEQ 4096
#define E 768
#define DK 64

typedef float f32x4 __attribute__((ext_vector_type(4)));
typedef float f32x16 __attribute__((ext_vector_type(16)));
typedef __bf16 bf16x8 __attribute__((ext_vector_type(8)));
typedef __bf16 bf16x4 __attribute__((ext_vector_type(4)));
typedef unsigned u32x2 __attribute__((ext_vector_type(2)));
typedef unsigned u32x4 __attribute__((ext_vector_type(4)));

#define MFMA16(a, b, c) __builtin_amdgcn_mfma_f32_16x16x32_bf16((a), (b), (c), 0, 0, 0)
#define MFMA32(a, b, c) __builtin_amdgcn_mfma_f32_32x32x16_bf16((a), (b), (c), 0, 0, 0)

// log2(e) / sqrt(dk); folded into K weights at wsplit time.
#define SCL 0.18033688011112042f
// defer-max threshold in log2 units: P bounded by 2^10.8
#define DEFER 10.8f

#define PART_SZ 4352  // 2*16*64 bf16 (4096B) + m[32],l[32] f32 (256B)

__device__ __forceinline__ void gload16(const void* g, void* l) {
    __builtin_amdgcn_global_load_lds(
        (const __attribute__((address_space(1))) void*)g,
        (__attribute__((address_space(3))) void*)l, 16, 0, 0);
}

__device__ __forceinline__ void block_sync() {
    __builtin_amdgcn_sched_barrier(0);
    __builtin_amdgcn_s_barrier();
    __builtin_amdgcn_sched_barrier(0);
}

__device__ __forceinline__ unsigned cvtpk(float lo, float hi) {
    unsigned r;
    asm("v_cvt_pk_bf16_f32 %0, %1, %2" : "=v"(r) : "v"(lo), "v"(hi));
    return r;
}
__device__ __forceinline__ u32x2 plswap(unsigned a, unsigned b) {
    return __builtin_amdgcn_permlane32_swap(a, b, false, false);
}
__device__ __forceinline__ float xhalf_max(float v) {
    u32x2 r = plswap(__float_as_uint(v), __float_as_uint(v));
    return fmaxf(__uint_as_float(r.x), __uint_as_float(r.y));
}
__device__ __forceinline__ float xhalf_add(float v) {
    u32x2 r = plswap(__float_as_uint(v), __float_as_uint(v));
    return __uint_as_float(r.x) + __uint_as_float(r.y);
}

// ---------------------------------------------------------------------------
// Kernel 1: weight split/transpose via LDS 64x64 tile (coalesced both
// sides). 144 blocks only — the x hi/lo split is now folded into proj.
// ---------------------------------------------------------------------------
__global__ __launch_bounds__(256) void prep_kernel(
    const float* __restrict__ qp, const float* __restrict__ kp,
    const float* __restrict__ vp,
    __bf16* __restrict__ wtq_h, __bf16* __restrict__ wtq_l,
    __bf16* __restrict__ wtk_h, __bf16* __restrict__ wtk_l,
    __bf16* __restrict__ wtv_h) {
    __shared__ float tl[64][65];

    const int h = blockIdx.x / 12;
    const int kt = blockIdx.x % 12;
    const int c = threadIdx.x & 63;
    const int r4 = threadIdx.x >> 6;

#pragma unroll
    for (int mat = 0; mat < 3; ++mat) {
        const float* src = ((mat == 0) ? qp : (mat == 1) ? kp : vp)
                         + (size_t)h * E * DK + (size_t)kt * 64 * DK;
        __syncthreads();
#pragma unroll
        for (int i = 0; i < 16; ++i) {
            int row = i * 4 + r4;
            tl[row][c] = src[row * DK + c];
        }
        __syncthreads();
#pragma unroll
        for (int i = 0; i < 16; ++i) {
            int n = i * 4 + r4;
            float v = tl[c][n];
            size_t o = (size_t)h * DK * E + (size_t)n * E + kt * 64 + c;
            if (mat == 0) {
                __bf16 hh = (__bf16)v;
                wtq_h[o] = hh;
                wtq_l[o] = (__bf16)(v - (float)hh);
            } else if (mat == 1) {
                float kk = v * SCL;
                __bf16 hh = (__bf16)kk;
                wtk_h[o] = hh;
                wtk_l[o] = (__bf16)(kk - (float)hh);
            } else {
                wtv_h[o] = (__bf16)v;
            }
        }
    }
}

// ---------------------------------------------------------------------------
// Kernel 2: fused Q+K+V projection (r18-proven structure). Block = 128 thr
// (2 waves x 32 rows), 64 rows/block, grid 768. x read DIRECTLY as f32 and
// split to bf16 hi/lo in-register (xsplit stage deleted: saves a pipeline
// phase + ~37MB of traffic). Q row-major; K,V FRAGMENT-LINEAR.
// ---------------------------------------------------------------------------
__global__ __launch_bounds__(128, 2) void proj_kernel(
    const float* __restrict__ x,
    const __bf16* __restrict__ wq_h_g, const __bf16* __restrict__ wq_l_g,
    const __bf16* __restrict__ wk_h_g, const __bf16* __restrict__ wk_l_g,
    const __bf16* __restrict__ wv_g,
    __bf16* __restrict__ qh_o, __bf16* __restrict__ ql_o,
    __bf16* __restrict__ kh_o, __bf16* __restrict__ kl_o,
    __bf16* __restrict__ vt_o) {
    __shared__ char wlds[2][20480];  // [buf][ Wqh | Wql | Wkh | Wkl | Wv ]

    const int wg = (blockIdx.x & 7) * 96 + (blockIdx.x >> 3);  // 768 = 8 x 96
    const int head = wg >> 6;
    const int rb = wg & 63;
    const int wave = threadIdx.x >> 6;  // 0..1
    const int lane = threadIdx.x & 63;
    const int lrow = lane & 15;
    const int lk8 = (lane >> 4) * 8;
    const int g4 = (lane >> 4) * 4;
    const int rowbase = rb * 64 + wave * 32;  // wave's 32 rows

    const char* bases[5] = {
        (const char*)(wq_h_g + head * DK * E), (const char*)(wq_l_g + head * DK * E),
        (const char*)(wk_h_g + head * DK * E), (const char*)(wk_l_g + head * DK * E),
        (const char*)(wv_g + head * DK * E)};
    const int srow = lane >> 2;
    const int scol = (lane & 3) * 16;

    auto STAGE = [&](int buf, int ks) {
#pragma unroll
        for (int r = 0; r < 10; ++r) {
            int q = wave * 10 + r;  // 0..19
            const char* src = bases[q >> 2] + (size_t)((q & 3) * 16 + srow) * (E * 2) + ks * 64 + scol;
            gload16(src, wlds[buf] + q * 1024 + lane * 16);
        }
    };

    f32x4 accq[2][4], acck[2][4], accv[2][4];
#pragma unroll
    for (int rt = 0; rt < 2; ++rt)
#pragma unroll
        for (int f = 0; f < 4; ++f) {
            accq[rt][f] = (f32x4){0.f, 0.f, 0.f, 0.f};
            acck[rt][f] = (f32x4){0.f, 0.f, 0.f, 0.f};
            accv[rt][f] = (f32x4){0.f, 0.f, 0.f, 0.f};
        }

    // x loaded as f32 (float4 pairs), split hi/lo in-register.
    f32x4 xa[2], xb[2], xan[2], xbn[2];
    auto LOADX = [&](int ks, f32x4* a, f32x4* b) {
#pragma unroll
        for (int rt = 0; rt < 2; ++rt) {
            const float* xp = x + (size_t)(rowbase + rt * 16 + lrow) * E + ks * 32 + lk8;
            a[rt] = *(const f32x4*)(xp);
            b[rt] = *(const f32x4*)(xp + 4);
        }
    };
    bf16x8 ah[2], al[2];
    auto CVT = [&](const f32x4* a, const f32x4* b) {
#pragma unroll
        for (int rt = 0; rt < 2; ++rt) {
#pragma unroll
            for (int j = 0; j < 4; ++j) {
                float v0 = a[rt][j], v1 = b[rt][j];
                __bf16 h0 = (__bf16)v0, h1 = (__bf16)v1;
                ah[rt][j] = h0;
                ah[rt][4 + j] = h1;
                al[rt][j] = (__bf16)(v0 - (float)h0);
                al[rt][4 + j] = (__bf16)(v1 - (float)h1);
            }
        }
    };

    LOADX(0, xa, xb);
    STAGE(0, 0);
    int buf = 0;
    for (int ks = 0; ks < 24; ++ks) {
        if (ks < 23) {
            LOADX(ks + 1, xan, xbn);
            STAGE(buf ^ 1, ks + 1);
            asm volatile("s_waitcnt vmcnt(14)" ::: "memory");  // 10 stage + 4 x
        } else {
            asm volatile("s_waitcnt vmcnt(0)" ::: "memory");
        }
        CVT(xa, xb);
        block_sync();
#pragma unroll
        for (int f = 0; f < 4; ++f) {
            int bo = (f * 16 + lrow) * 64 + lk8 * 2;
            bf16x8 bqh = *(const bf16x8*)(wlds[buf] + bo);
            bf16x8 bql = *(const bf16x8*)(wlds[buf] + 4096 + bo);
            bf16x8 bkh = *(const bf16x8*)(wlds[buf] + 8192 + bo);
            bf16x8 bkl = *(const bf16x8*)(wlds[buf] + 12288 + bo);
            bf16x8 bv  = *(const bf16x8*)(wlds[buf] + 16384 + bo);
#pragma unroll
            for (int rt = 0; rt < 2; ++rt) {
                accq[rt][f] = MFMA16(ah[rt], bqh, accq[rt][f]);
                accq[rt][f] = MFMA16(ah[rt], bql, accq[rt][f]);
                accq[rt][f] = MFMA16(al[rt], bqh, accq[rt][f]);
                acck[rt][f] = MFMA16(ah[rt], bkh, acck[rt][f]);
                acck[rt][f] = MFMA16(ah[rt], bkl, acck[rt][f]);
                acck[rt][f] = MFMA16(al[rt], bkh, acck[rt][f]);
                accv[rt][f] = MFMA16(bv, ah[rt], accv[rt][f]);  // D[d][s]
            }
        }
        block_sync();
        if (ks < 23) {
#pragma unroll
            for (int rt = 0; rt < 2; ++rt) {
                xa[rt] = xan[rt];
                xb[rt] = xbn[rt];
            }
        }
        buf ^= 1;
    }

    char* khb = (char*)kh_o + (size_t)head * SEQ * DK * 2;
    char* klb = (char*)kl_o + (size_t)head * SEQ * DK * 2;
    char* vb = (char*)vt_o + (size_t)head * DK * SEQ * 2;
#pragma unroll
    for (int rt = 0; rt < 2; ++rt)
#pragma unroll
        for (int f = 0; f < 4; ++f)
#pragma unroll
            for (int r = 0; r < 4; ++r) {
                int srow_o = rowbase + rt * 16 + g4 + r;
                int d = f * 16 + lrow;
                size_t o = (size_t)head * SEQ * DK + (size_t)srow_o * DK + d;
                float qv = accq[rt][f][r];
                __bf16 qhh = (__bf16)qv;
                qh_o[o] = qhh;
                ql_o[o] = (__bf16)(qv - (float)qhh);
                size_t ko = (size_t)(srow_o >> 6) * 8192 + ((srow_o >> 5) & 1) * 4096
                          + (size_t)f * 1024
                          + ((srow_o & 31) + 32 * ((lrow >> 3) & 1)) * 16 + (lrow & 7) * 2;
                float kv = acck[rt][f][r];
                __bf16 khh = (__bf16)kv;
                *(__bf16*)(khb + ko) = khh;
                *(__bf16*)(klb + ko) = (__bf16)(kv - (float)khh);
                int vd = f * 16 + g4 + r;
                int vs = rowbase + rt * 16 + lrow;
                size_t vo = (size_t)(vs >> 6) * 8192 + ((vd >> 5) & 1) * 4096
                          + ((vs >> 4) & 3) * 1024
                          + ((vd & 31) + 32 * ((vs >> 3) & 1)) * 16 + (vs & 7) * 2;
                *(__bf16*)(vb + vo) = (__bf16)accv[rt][f][r];
            }
}

// ---------------------------------------------------------------------------
// Kernel 3a: attention partials — r15/r20 proven config (86us, schedule-
// invariant): fine-grained equal-work split-KV, 6912 independent waves,
// no LDS, no barriers. Split-major within-tier task layout (r20).
// ---------------------------------------------------------------------------
__global__ __launch_bounds__(256, 2) void attn_part_kernel(
    const __bf16* __restrict__ qh, const __bf16* __restrict__ ql,
    const __bf16* __restrict__ kh, const __bf16* __restrict__ kl,
    const __bf16* __restrict__ vt,
    char* __restrict__ part) {
    const int blk = (blockIdx.x & 7) * 216 + (blockIdx.x >> 3);  // 1728 = 8x216
    const int wave = threadIdx.x >> 6;
    const int task = blk * 4 + wave;
    const int lane = threadIdx.x & 63;
    const int lq = lane & 31;
    const int lh = lane >> 5;

    const int head = task / 576;
    const int t = task - head * 576;
    int g = 0;
#pragma unroll 8
    for (int gg = 1; gg <= 7; ++gg)
        if (t >= 16 * gg * (gg + 1) / 2) g = gg;
    const int nsp = g + 1;
    const int u = t - 16 * g * (g + 1) / 2;
    const int split = u >> 4;            // split-major (r20)
    const int w = 16 * g + (u & 15);
    const int ktot = (w >> 1) + 1;
    const int lo = (split * ktot) / nsp;
    const int hi = ((split + 1) * ktot) / nsp;
    const int rowbase = w * 32;

    const size_t hoff = (size_t)head * SEQ * DK;

    bf16x8 qBh[4], qBl[4];
    {
        const __bf16* qph = qh + hoff + (size_t)(rowbase + lq) * DK + lh * 8;
        const __bf16* qpl = ql + hoff + (size_t)(rowbase + lq) * DK + lh * 8;
#pragma unroll
        for (int ds = 0; ds < 4; ++ds) {
            qBh[ds] = *(const bf16x8*)(qph + ds * 16);
            qBl[ds] = *(const bf16x8*)(qpl + ds * 16);
        }
    }

    const char* kh_p = (const char*)(kh + hoff) + (size_t)lo * 8192 + lane * 16;
    const char* kl_p = (const char*)(kl + hoff) + (size_t)lo * 8192 + lane * 16;
    const char* vt_p = (const char*)(vt + (size_t)head * DK * SEQ) + (size_t)lo * 8192 + lane * 16;

    f32x16 O0 = (f32x16)0.0f, O1 = (f32x16)0.0f;
    float m = -3.0e38f, lsum = 0.f;

    for (int tt = lo; tt < hi; ++tt) {
        const int kb = tt * 64;

        f32x16 s0 = (f32x16)0.0f, s1 = (f32x16)0.0f;
#pragma unroll
        for (int ds = 0; ds < 4; ++ds) {
            bf16x8 ah0 = *(const bf16x8*)(kh_p + ds * 1024);
            bf16x8 al0 = *(const bf16x8*)(kl_p + ds * 1024);
            bf16x8 ah1 = *(const bf16x8*)(kh_p + 4096 + ds * 1024);
            bf16x8 al1 = *(const bf16x8*)(kl_p + 4096 + ds * 1024);
            s0 = MFMA32(ah0, qBh[ds], s0);
            s1 = MFMA32(ah1, qBh[ds], s1);
            s0 = MFMA32(al0, qBh[ds], s0);
            s1 = MFMA32(al1, qBh[ds], s1);
            s0 = MFMA32(ah0, qBl[ds], s0);
            s1 = MFMA32(ah1, qBl[ds], s1);
        }

        bf16x8 v00 = *(const bf16x8*)(vt_p + 0);
        bf16x8 v01 = *(const bf16x8*)(vt_p + 1024);
        bf16x8 v10 = *(const bf16x8*)(vt_p + 2048);
        bf16x8 v11 = *(const bf16x8*)(vt_p + 3072);
        bf16x8 w00 = *(const bf16x8*)(vt_p + 4096);
        bf16x8 w01 = *(const bf16x8*)(vt_p + 5120);
        bf16x8 w10 = *(const bf16x8*)(vt_p + 6144);
        bf16x8 w11 = *(const bf16x8*)(vt_p + 7168);

        if (kb + 63 > rowbase) {
            int qa = rowbase + lq;
#pragma unroll
            for (int r = 0; r < 16; ++r) {
                int kp = kb + ((r & 3) + 8 * (r >> 2) + 4 * lh);
                if (kp > qa) s0[r] = -1.0e30f;
                if (kp + 32 > qa) s1[r] = -1.0e30f;
            }
        }

        float x0 = fmaxf(s0[0], s0[1]), x1 = fmaxf(s0[2], s0[3]);
        float x2 = fmaxf(s0[4], s0[5]), x3 = fmaxf(s0[6], s0[7]);
#pragma unroll
        for (int r = 8; r < 16; r += 4) {
            x0 = fmaxf(x0, fmaxf(s0[r], s0[r + 1]));
            x1 = fmaxf(x1, fmaxf(s0[r + 2], s0[r + 3]));
        }
#pragma unroll
        for (int r = 0; r < 16; r += 4) {
            x2 = fmaxf(x2, fmaxf(s1[r], s1[r + 1]));
            x3 = fmaxf(x3, fmaxf(s1[r + 2], s1[r + 3]));
        }
        float mx = xhalf_max(fmaxf(fmaxf(x0, x1), fmaxf(x2, x3)));

        if (!__all(mx - m <= DEFER)) {
            float mn = fmaxf(m, mx);
            float al = exp2f(m - mn);
            m = mn;
            lsum *= al;
#pragma unroll
            for (int r = 0; r < 16; ++r) {
                float a = __shfl(al, (r & 3) + 8 * (r >> 2) + 4 * lh);
                O0[r] *= a;
                O1[r] *= a;
            }
        }

        s0 = s0 - m;
        s1 = s1 - m;
#pragma unroll
        for (int r = 0; r < 16; ++r) {
            s0[r] = exp2f(s0[r]);
            s1[r] = exp2f(s1[r]);
        }
        {
            f32x16 sv = s0 + s1;
            float p0 = 0.f, p1 = 0.f;
#pragma unroll
            for (int r = 0; r < 16; r += 4) {
                p0 += sv[r] + sv[r + 1];
                p1 += sv[r + 2] + sv[r + 3];
            }
            lsum += p0 + p1;
        }

        unsigned W0 = cvtpk(s0[0], s0[1]), W1 = cvtpk(s0[2], s0[3]);
        unsigned W2 = cvtpk(s0[4], s0[5]), W3 = cvtpk(s0[6], s0[7]);
        unsigned W4 = cvtpk(s0[8], s0[9]), W5 = cvtpk(s0[10], s0[11]);
        unsigned W6 = cvtpk(s0[12], s0[13]), W7 = cvtpk(s0[14], s0[15]);
        u32x2 rA = plswap(W0, W2), rB = plswap(W1, W3);
        u32x2 rC = plswap(W4, W6), rD = plswap(W5, W7);
        bf16x8 p00 = __builtin_bit_cast(bf16x8, (u32x4){rA.x, rB.x, rA.y, rB.y});
        bf16x8 p01 = __builtin_bit_cast(bf16x8, (u32x4){rC.x, rD.x, rC.y, rD.y});
        W0 = cvtpk(s1[0], s1[1]); W1 = cvtpk(s1[2], s1[3]);
        W2 = cvtpk(s1[4], s1[5]); W3 = cvtpk(s1[6], s1[7]);
        W4 = cvtpk(s1[8], s1[9]); W5 = cvtpk(s1[10], s1[11]);
        W6 = cvtpk(s1[12], s1[13]); W7 = cvtpk(s1[14], s1[15]);
        rA = plswap(W0, W2); rB = plswap(W1, W3);
        rC = plswap(W4, W6); rD = plswap(W5, W7);
        bf16x8 p10 = __builtin_bit_cast(bf16x8, (u32x4){rA.x, rB.x, rA.y, rB.y});
        bf16x8 p11 = __builtin_bit_cast(bf16x8, (u32x4){rC.x, rD.x, rC.y, rD.y});

        O0 = MFMA32(p00, v00, O0);
        O0 = MFMA32(p01, v01, O0);
        O0 = MFMA32(p10, v10, O0);
        O0 = MFMA32(p11, v11, O0);
        O1 = MFMA32(p00, w00, O1);
        O1 = MFMA32(p01, w01, O1);
        O1 = MFMA32(p10, w10, O1);
        O1 = MFMA32(p11, w11, O1);

        kh_p += 8192;
        kl_p += 8192;
        vt_p += 8192;
    }

    char* pb = part + (size_t)task * PART_SZ;
    unsigned* ph = (unsigned*)pb;
#pragma unroll
    for (int r = 0; r < 16; r += 2) {
        ph[(r >> 1) * 64 + lane] = cvtpk(O0[r], O0[r + 1]);
        ph[512 + (r >> 1) * 64 + lane] = cvtpk(O1[r], O1[r + 1]);
    }
    float lf = xhalf_add(lsum);
    float* pm = (float*)(pb + 4096);
    if (lane < 32) {
        pm[lq] = m;
        pm[32 + lq] = lf;
    }
}

// ---------------------------------------------------------------------------
// Kernel 3b: combine partials — exact flash merge per (head, window).
// Split-major task layout (r20): partial s at tb + s*16.
// ---------------------------------------------------------------------------
__global__ __launch_bounds__(256) void attn_comb_kernel(
    const char* __restrict__ part, float* __restrict__ out) {
    const int W = blockIdx.x;  // 0..1535
    const int head = W >> 7, w = W & 127;
    const int g = w >> 4;
    const int nsp = g + 1;
    const int tb = head * 576 + 16 * g * (g + 1) / 2 + (w & 15);

    const int tid = threadIdx.x;
    const int row = tid >> 3;
    const int d0 = (tid & 7) * 8;
    const int lane0 = (d0 & 31) + 32 * ((row >> 2) & 1);
    const int r = (row & 3) + 4 * (row >> 3);
    const int word = (r >> 1) * 64;
    const int hi16 = r & 1;
    const char* p0 = part + (size_t)tb * PART_SZ;

    float mstar = -3.0e38f;
    for (int s = 0; s < nsp; ++s) {
        const float* pm = (const float*)(p0 + (size_t)s * 16 * PART_SZ + 4096);
        mstar = fmaxf(mstar, pm[row]);
    }

    float acc[8] = {0.f, 0.f, 0.f, 0.f, 0.f, 0.f, 0.f, 0.f};
    float lt = 0.f;
    for (int s = 0; s < nsp; ++s) {
        const char* ps = p0 + (size_t)s * 16 * PART_SZ;
        const float* pm = (const float*)(ps + 4096);
        float wgt = exp2f(pm[row] - mstar);
        lt += wgt * pm[32 + row];
        const unsigned* pw = (const unsigned*)(ps + (d0 >> 5) * 2048);
        u32x4 a = *(const u32x4*)(pw + word + lane0);
        u32x4 b = *(const u32x4*)(pw + word + lane0 + 4);
#pragma unroll
        for (int j = 0; j < 8; ++j) {
            unsigned u = (j < 4) ? a[j] : b[j - 4];
            unsigned bits = hi16 ? (u & 0xffff0000u) : (u << 16);
            acc[j] += wgt * __uint_as_float(bits);
        }
    }
    float inv = 1.0f / lt;
    size_t o = (size_t)head * SEQ * DK + (size_t)(w * 32 + row) * DK + d0;
#pragma unroll
    for (int j = 0; j < 8; ++j) out[o + j] = acc[j] * inv;
}

// ---------------------------------------------------------------------------
extern "C" void kernel_launch(void* const* d_in, const int* in_sizes, int n_in,
                              void* d_out, int out_size, void* d_ws, size_t ws_size,
                              hipStream_t stream) {
    const float* x = (const float*)d_in[0];
    const float* qp = (const float*)d_in[1];
    const float* kp = (const float*)d_in[2];
    const float* vp = (const float*)d_in[3];
    float* out = (float*)d_out;

    const size_t WT_SZ = (size_t)NH * DK * E * 2;     // 1,179,648 B
    const size_t QKV_SZ = (size_t)NH * SEQ * DK * 2;  // 6,291,456 B
    const size_t X_SZ = (size_t)SEQ * E * 2;          // 6,291,456 B
    char* ws = (char*)d_ws;
    __bf16* wtq_h = (__bf16*)(ws + 0 * WT_SZ);
    __bf16* wtq_l = (__bf16*)(ws + 1 * WT_SZ);
    __bf16* wtk_h = (__bf16*)(ws + 2 * WT_SZ);
    __bf16* wtk_l = (__bf16*)(ws + 3 * WT_SZ);
    __bf16* wtv_h = (__bf16*)(ws + 4 * WT_SZ);
    char* px = ws + 5 * WT_SZ;  // xh/xl slots retained (unused) to keep the
    char* p2 = px + 2 * X_SZ;   // ws-verified layout identical to r15-r20
    __bf16* qh = (__bf16*)(p2 + 0 * QKV_SZ);
    __bf16* ql = (__bf16*)(p2 + 1 * QKV_SZ);
    __bf16* kh = (__bf16*)(p2 + 2 * QKV_SZ);
    __bf16* kl = (__bf16*)(p2 + 3 * QKV_SZ);
    __bf16* vt = (__bf16*)(p2 + 4 * QKV_SZ);
    char* part = p2 + 5 * QKV_SZ;  // 6912 x 4352 = 30,081,024 B (ws-verified)

    hipLaunchKernelGGL(prep_kernel, dim3(144), dim3(256), 0, stream,
                       qp, kp, vp, wtq_h, wtq_l, wtk_h, wtk_l, wtv_h);
    hipLaunchKernelGGL(proj_kernel, dim3(768), dim3(128), 0, stream,
                       x, wtq_h, wtq_l, wtk_h, wtk_l, wtv_h, qh, ql, kh, kl, vt);
    hipLaunchKernelGGL(attn_part_kernel, dim3(1728), dim3(256), 0, stream,
                       qh, ql, kh, kl, vt, part);
    hipLaunchKernelGGL(attn_comb_kernel, dim3(1536), dim3(256), 0, stream,
                       part, out);
}